// Round 4
// baseline (243.078 us; speedup 1.0000x reference)
//
#include <hip/hip_runtime.h>
#include <hip/hip_bf16.h>

// Problem constants
constexpr int B_ = 4, N_ = 2048, D_ = 768, OUT_ = 768;
constexpr int M_ = B_ * N_;  // 8192 rows for the fused QKV GEMM

typedef __attribute__((ext_vector_type(8))) short short8;   // 8 bf16 (4 VGPRs)
typedef __attribute__((ext_vector_type(4))) float floatx4;  // MFMA C/D frag

__device__ __forceinline__ unsigned short f2bfu(float f) {
    union { __hip_bfloat16 b; unsigned short u; } cv;
    cv.b = __float2bfloat16(f);
    return cv.u;
}

#define GLOAD_LDS16(g, l)                                                     \
    __builtin_amdgcn_global_load_lds(                                         \
        (const __attribute__((address_space(1))) void*)(g),                   \
        (__attribute__((address_space(3))) void*)(l), 16, 0, 0)

// ---------------------------------------------------------------------------
// Double-buffered NT-GEMM core, BK=32, ONE barrier per iter.
// Pipeline: [barrier] -> prefetch next tile into buf^1 -> ds_read+MFMA on buf.
// The vmcnt(0) drain at each barrier therefore waits on loads issued a full
// compute-phase earlier (exposed latency ~= max(0, L - T_compute)), instead
// of the round-3 structure where loads were issued right before the barrier.
// WAR safety: after barrier at iter k, all waves' iter k-1 ds_reads have
// retired (lgkmcnt(0) drain at the barrier), so overwriting buf^1 is safe.
//
// LDS: linear [row][slot] per 32-K tile; global chunk c of row r is staged at
// slot c with the SWIZZLE folded into the global address: slot c holds global
// chunk c ^ key(r), key(r) = (r + (r>>2)) & 3. Staging LDS writes are linear
// (conflict-free); frag reads spread across all bank quads (2-way max).
// Wave tile (BM/2) x 64, 2x2 waves. BM=64 -> acc 2x4, ~24KB LDS, 5-6 blk/CU.
// ---------------------------------------------------------------------------
template <int BM>
__device__ __forceinline__ void gemm_core_db(
    const __hip_bfloat16* __restrict__ a_base, int lda,
    const __hip_bfloat16* __restrict__ b_base, int ldb,
    int m0, int n0, int K,
    __hip_bfloat16* As, __hip_bfloat16* Bs,  // 2 bufs each: BM*32, 128*32
    floatx4 (&acc)[BM / 32][4]) {
    const int tid  = threadIdx.x;
    const int wave = tid >> 6, lane = tid & 63;
    const int wm = (wave >> 1) * (BM / 2), wn = (wave & 1) * 64;
    const int lrow = lane & 15, kq = lane >> 4;

    auto stage = [&](int buf, int k0) {
        // A tile: BM x 32 bf16 = BM*4 16B chunks; BM/64 insts/thread
#pragma unroll
        for (int i = 0; i < BM / 64; ++i) {
            const int u = i * 256 + tid;
            const int row = u >> 2;
            const int cg = (u & 3) ^ ((row + (row >> 2)) & 3);
            const __hip_bfloat16* g =
                a_base + (size_t)(m0 + row) * lda + k0 + cg * 8;
            GLOAD_LDS16(g, As + buf * (BM * 32) + (i * 256 + wave * 64) * 8);
        }
        // B tile: 128 x 32 bf16; 2 insts/thread
#pragma unroll
        for (int i = 0; i < 2; ++i) {
            const int u = i * 256 + tid;
            const int row = u >> 2;
            const int cg = (u & 3) ^ ((row + (row >> 2)) & 3);
            const __hip_bfloat16* g =
                b_base + (size_t)(n0 + row) * ldb + k0 + cg * 8;
            GLOAD_LDS16(g, Bs + buf * (128 * 32) + (i * 256 + wave * 64) * 8);
        }
    };

    stage(0, 0);
    int buf = 0;
    for (int k0 = 0; k0 < K; k0 += 32) {
        __syncthreads();  // waits own prefetch (issued ~1 compute-phase ago)
        if (k0 + 32 < K) stage(buf ^ 1, k0 + 32);

        const __hip_bfloat16* Ab = As + buf * (BM * 32);
        const __hip_bfloat16* Bb = Bs + buf * (128 * 32);
        short8 af[BM / 32], bfr[4];
#pragma unroll
        for (int t = 0; t < BM / 32; ++t) {
            const int row = wm + t * 16 + lrow;
            const int slot = kq ^ ((row + (row >> 2)) & 3);
            af[t] = *(const short8*)(Ab + row * 32 + slot * 8);
        }
#pragma unroll
        for (int t = 0; t < 4; ++t) {
            const int row = wn + t * 16 + lrow;
            const int slot = kq ^ ((row + (row >> 2)) & 3);
            bfr[t] = *(const short8*)(Bb + row * 32 + slot * 8);
        }
#pragma unroll
        for (int mi = 0; mi < BM / 32; ++mi)
#pragma unroll
            for (int ni = 0; ni < 4; ++ni)
                acc[mi][ni] = __builtin_amdgcn_mfma_f32_16x16x32_bf16(
                    af[mi], bfr[ni], acc[mi][ni], 0, 0, 0);
        buf ^= 1;
    }
}

// ---------------------------------------------------------------------------
// Kernel 0: prep. Blocks [0,3072): x fp32 -> bf16. Blocks [3072,4800):
// w[s][d][o] fp32 -> wt[s][o][d] bf16 via 32x32 LDS transpose.
// ---------------------------------------------------------------------------
__global__ __launch_bounds__(256)
void prep(const float* __restrict__ x, const float* __restrict__ w,
          __hip_bfloat16* __restrict__ xb, __hip_bfloat16* __restrict__ wt) {
    __shared__ float t[32][33];
    const int tid = threadIdx.x;
    if (blockIdx.x < 3072) {
        const size_t i = (size_t)blockIdx.x * 2048 + (size_t)tid * 8;
        float4 a = *(const float4*)(x + i);
        float4 b = *(const float4*)(x + i + 4);
        *(ushort4*)((unsigned short*)xb + i) =
            make_ushort4(f2bfu(a.x), f2bfu(a.y), f2bfu(a.z), f2bfu(a.w));
        *(ushort4*)((unsigned short*)xb + i + 4) =
            make_ushort4(f2bfu(b.x), f2bfu(b.y), f2bfu(b.z), f2bfu(b.w));
    } else {
        const int bid = blockIdx.x - 3072;
        const int s = bid / 576, rem = bid % 576;
        const int d0 = (rem / 24) * 32, o0 = (rem % 24) * 32;
        const int tx = tid & 31, ty = tid >> 5;  // 32 x 8
        const float* ws = w + (size_t)s * D_ * OUT_;
        __hip_bfloat16* wts = wt + (size_t)s * OUT_ * D_;
#pragma unroll
        for (int i = 0; i < 4; ++i)
            t[ty + 8 * i][tx] = ws[(size_t)(d0 + ty + 8 * i) * OUT_ + o0 + tx];
        __syncthreads();
#pragma unroll
        for (int i = 0; i < 4; ++i)
            wts[(size_t)(o0 + ty + 8 * i) * D_ + d0 + tx] =
                __float2bfloat16(t[tx][ty + 8 * i]);
    }
}

// ---------------------------------------------------------------------------
// Kernel 1: QKV projection (NT, BM=64, dbuf). grid (128, 6, 3).
// Epilogue via LDS roundtrip (reuses the 24KB loop LDS):
//   s<2: E[m][n] stride 136 -> coalesced short8 q/k stores
//   s=2: E[n][m] stride 88  -> coalesced short8 vt stores (transposed write)
// ---------------------------------------------------------------------------
__global__ __launch_bounds__(256)
void qkv_mfma(const __hip_bfloat16* __restrict__ xb,
              const __hip_bfloat16* __restrict__ wt,
              __hip_bfloat16* __restrict__ q, __hip_bfloat16* __restrict__ k,
              __hip_bfloat16* __restrict__ vt) {
    __shared__ __align__(16) char smem[24576];
    __hip_bfloat16* As = (__hip_bfloat16*)smem;            // 2 x 4KB
    __hip_bfloat16* Bs = (__hip_bfloat16*)(smem + 8192);   // 2 x 8KB
    const int s = blockIdx.z;
    const int m0 = blockIdx.x * 64, n0 = blockIdx.y * 128;
    floatx4 acc[2][4] = {};
    gemm_core_db<64>(xb, D_, wt + (size_t)s * OUT_ * D_, D_, m0, n0, D_, As,
                     Bs, acc);

    const int tid = threadIdx.x, wave = tid >> 6, lane = tid & 63;
    const int wm = (wave >> 1) * 32, wn = (wave & 1) * 64;
    const int lrow = lane & 15, kq = lane >> 4;
    unsigned short* E = (unsigned short*)smem;
    __syncthreads();  // loop LDS reuse: last iter had no trailing barrier

    if (s < 2) {  // E[m][n], 64 x 136
#pragma unroll
        for (int mi = 0; mi < 2; ++mi)
#pragma unroll
            for (int ni = 0; ni < 4; ++ni) {
                const int n = wn + ni * 16 + lrow;
#pragma unroll
                for (int r = 0; r < 4; ++r)
                    E[(wm + mi * 16 + kq * 4 + r) * 136 + n] =
                        f2bfu(acc[mi][ni][r]);
            }
        __syncthreads();
        __hip_bfloat16* out = (s == 0) ? q : k;
#pragma unroll
        for (int i = 0; i < 4; ++i) {
            const int u = i * 256 + tid, row = u >> 4, c = u & 15;
            short8 v = *(const short8*)(E + row * 136 + c * 8);
            *(short8*)(out + (size_t)(m0 + row) * OUT_ + n0 + c * 8) = v;
        }
    } else {  // E[n][m], 128 x 88 (16B-aligned rows: 88*2=176=11*16)
#pragma unroll
        for (int mi = 0; mi < 2; ++mi)
#pragma unroll
            for (int ni = 0; ni < 4; ++ni) {
                const int n = wn + ni * 16 + lrow;
                *(ushort4*)(E + n * 88 + wm + mi * 16 + kq * 4) =
                    make_ushort4(f2bfu(acc[mi][ni][0]), f2bfu(acc[mi][ni][1]),
                                 f2bfu(acc[mi][ni][2]), f2bfu(acc[mi][ni][3]));
            }
        __syncthreads();
        const int b = m0 >> 11, j0 = m0 & 2047;
#pragma unroll
        for (int i = 0; i < 4; ++i) {
            const int u = i * 256 + tid, nrow = u >> 3, c = u & 7;
            short8 v = *(const short8*)(E + nrow * 88 + c * 8);
            *(short8*)(vt + ((size_t)b * OUT_ + n0 + nrow) * N_ + j0 + c * 8) =
                v;
        }
    }
}

// ---------------------------------------------------------------------------
// Kernel 2: scores (NT, BM=64, dbuf). grid (32, 16, 4). fp32 dword stores.
// ---------------------------------------------------------------------------
__global__ __launch_bounds__(256)
void scores_mfma(const __hip_bfloat16* __restrict__ q,
                 const __hip_bfloat16* __restrict__ k,
                 float* __restrict__ S) {
    __shared__ __align__(16) __hip_bfloat16 As[2 * 64 * 32];
    __shared__ __align__(16) __hip_bfloat16 Bs[2 * 128 * 32];
    const int b = blockIdx.z;
    const int m0 = blockIdx.x * 64, n0 = blockIdx.y * 128;
    floatx4 acc[2][4] = {};
    gemm_core_db<64>(q + (size_t)b * N_ * OUT_, OUT_,
                     k + (size_t)b * N_ * OUT_, OUT_, m0, n0, OUT_, As, Bs,
                     acc);

    const int tid = threadIdx.x, wave = tid >> 6, lane = tid & 63;
    const int wm = (wave >> 1) * 32, wn = (wave & 1) * 64;
    const int lrow = lane & 15, kq = lane >> 4;
    float* Sb = S + (size_t)b * N_ * N_;
#pragma unroll
    for (int mi = 0; mi < 2; ++mi)
#pragma unroll
        for (int ni = 0; ni < 4; ++ni) {
            const int j = n0 + wn + ni * 16 + lrow;
#pragma unroll
            for (int r = 0; r < 4; ++r) {
                const int i = m0 + wm + mi * 16 + kq * 4 + r;
                Sb[(size_t)i * N_ + j] = acc[mi][ni][r] * 0.125f;
            }
        }
}

// ---------------------------------------------------------------------------
// Kernel 3: row softmax, fp32 in -> bf16 P in-place at row start (stride 4096
// shorts). All reads complete before the post-sum barrier; writes after.
// ---------------------------------------------------------------------------
__global__ __launch_bounds__(256)
void softmax_rows_bf16(float* __restrict__ S) {
    __shared__ float red[8];
    const int row = blockIdx.x;
    float* p = S + (size_t)row * (size_t)N_;
    const int tid = threadIdx.x;

    float4* p4 = (float4*)p;
    float4 a = p4[tid];
    float4 b = p4[tid + 256];

    float m = fmaxf(fmaxf(fmaxf(a.x, a.y), fmaxf(a.z, a.w)),
                    fmaxf(fmaxf(b.x, b.y), fmaxf(b.z, b.w)));
#pragma unroll
    for (int off = 32; off > 0; off >>= 1) m = fmaxf(m, __shfl_xor(m, off, 64));
    const int wid = tid >> 6, lane = tid & 63;
    if (lane == 0) red[wid] = m;
    __syncthreads();
    if (tid == 0) red[4] = fmaxf(fmaxf(red[0], red[1]), fmaxf(red[2], red[3]));
    __syncthreads();
    m = red[4];

    a.x = __expf(a.x - m); a.y = __expf(a.y - m);
    a.z = __expf(a.z - m); a.w = __expf(a.w - m);
    b.x = __expf(b.x - m); b.y = __expf(b.y - m);
    b.z = __expf(b.z - m); b.w = __expf(b.w - m);

    float s = a.x + a.y + a.z + a.w + b.x + b.y + b.z + b.w;
#pragma unroll
    for (int off = 32; off > 0; off >>= 1) s += __shfl_xor(s, off, 64);
    if (lane == 0) red[wid] = s;
    __syncthreads();
    if (tid == 0) red[5] = red[0] + red[1] + red[2] + red[3];
    __syncthreads();  // all reads precede any write
    const float r = 1.0f / red[5];

    ushort4* o4 = (ushort4*)p;
    o4[tid] = make_ushort4(f2bfu(a.x * r), f2bfu(a.y * r),
                           f2bfu(a.z * r), f2bfu(a.w * r));
    o4[tid + 256] = make_ushort4(f2bfu(b.x * r), f2bfu(b.y * r),
                                 f2bfu(b.z * r), f2bfu(b.w * r));
}

// ---------------------------------------------------------------------------
// Kernel 4: out = P.V (NT, BM=64, dbuf): A = P (lda 4096 shorts), B = vt.
// grid (32, 6, 4). K=2048 -> 64 iters (best pipeline amortization).
// ---------------------------------------------------------------------------
__global__ __launch_bounds__(256)
void pv_mfma(const __hip_bfloat16* __restrict__ P,
             const __hip_bfloat16* __restrict__ vt,
             float* __restrict__ out) {
    __shared__ __align__(16) __hip_bfloat16 As[2 * 64 * 32];
    __shared__ __align__(16) __hip_bfloat16 Bs[2 * 128 * 32];
    const int b = blockIdx.z;
    const int m0 = blockIdx.x * 64, n0 = blockIdx.y * 128;
    floatx4 acc[2][4] = {};
    gemm_core_db<64>(P + (size_t)b * N_ * 4096, 4096,
                     vt + (size_t)b * OUT_ * N_, N_, m0, n0, N_, As, Bs, acc);

    const int tid = threadIdx.x, wave = tid >> 6, lane = tid & 63;
    const int wm = (wave >> 1) * 32, wn = (wave & 1) * 64;
    const int lrow = lane & 15, kq = lane >> 4;
#pragma unroll
    for (int mi = 0; mi < 2; ++mi)
#pragma unroll
        for (int ni = 0; ni < 4; ++ni) {
            const int n = n0 + wn + ni * 16 + lrow;
#pragma unroll
            for (int r = 0; r < 4; ++r) {
                const int i = m0 + wm + mi * 16 + kq * 4 + r;
                out[((size_t)b * N_ + i) * OUT_ + n] = acc[mi][ni][r];
            }
        }
}

// ---------------------------------------------------------------------------
// ws layout (100 MB, unchanged):
//   [0: q bf16 12.6MB][12.6: k][25.2: vt][37.75: xb 12.6 | S fp32 67.1]
//   [50.3: wt 3.5MB]  (xb/wt dead once qkv_mfma completes; S overlays them)
// ---------------------------------------------------------------------------
extern "C" void kernel_launch(void* const* d_in, const int* in_sizes, int n_in,
                              void* d_out, int out_size, void* d_ws, size_t ws_size,
                              hipStream_t stream) {
    const float* x = (const float*)d_in[0];
    const float* w = (const float*)d_in[1];
    float* out = (float*)d_out;

    char* ws = (char*)d_ws;
    __hip_bfloat16* q  = (__hip_bfloat16*)ws;
    __hip_bfloat16* k  = q + (size_t)M_ * OUT_;
    __hip_bfloat16* vt = k + (size_t)M_ * OUT_;
    __hip_bfloat16* xb = vt + (size_t)M_ * OUT_;
    __hip_bfloat16* wt = xb + (size_t)M_ * D_;
    float* S = (float*)(ws + (size_t)3 * M_ * OUT_ * sizeof(__hip_bfloat16));

    prep<<<dim3(4800), dim3(256), 0, stream>>>(x, w, xb, wt);
    qkv_mfma<<<dim3(M_ / 64, OUT_ / 128, 3), dim3(256), 0, stream>>>(xb, wt, q, k, vt);
    scores_mfma<<<dim3(N_ / 64, N_ / 128, B_), dim3(256), 0, stream>>>(q, k, S);
    softmax_rows_bf16<<<dim3(M_), dim3(256), 0, stream>>>(S);
    pv_mfma<<<dim3(N_ / 64, OUT_ / 128, B_), dim3(256), 0, stream>>>(
        (const __hip_bfloat16*)S, vt, out);
}

// Round 5
// 200.227 us; speedup vs baseline: 1.2140x; 1.2140x over previous
//
#include <hip/hip_runtime.h>
#include <hip/hip_bf16.h>

// Problem constants
constexpr int B_ = 4, N_ = 2048, D_ = 768, OUT_ = 768;
constexpr int M_ = B_ * N_;  // 8192 rows for the fused QKV GEMM

typedef __attribute__((ext_vector_type(8))) short short8;   // 8 bf16 (4 VGPRs)
typedef __attribute__((ext_vector_type(4))) float floatx4;  // MFMA C/D frag

__device__ __forceinline__ unsigned short f2bfu(float f) {
    union { __hip_bfloat16 b; unsigned short u; } cv;
    cv.b = __float2bfloat16(f);
    return cv.u;
}

#define GLOAD_LDS16(g, l)                                                     \
    __builtin_amdgcn_global_load_lds(                                         \
        (const __attribute__((address_space(1))) void*)(g),                   \
        (__attribute__((address_space(3))) void*)(l), 16, 0, 0)

// ---------------------------------------------------------------------------
// NT-GEMM core (round-3 proven: 556 TF on qkv, 2.5e5 bank conflicts).
// BK=64, 2 barriers/iter, XOR-swizzled LDS (3-bit key, full 32-bank rows).
// C[BM x 128] += A[m0.., :K] * B[n0.., :K]^T, A/B row-major along K.
// LDS [row][slot]: slot c holds global chunk c ^ (row&7); staging linear and
// coalesced, frag reads spread across all banks (2-way max = free).
// 256 threads = 2x2 waves; wave tile (BM/2) x 64; BM in {64,128}.
// NOTE (round-4 lesson): do NOT convert this to single-barrier dbuf —
// __syncthreads drains vmcnt(0) incl. the just-issued prefetch, and smaller
// BK/BM cut MFMA-per-barrier; measured 243 vs 215 µs. Keep 2-barrier BK=64.
// ---------------------------------------------------------------------------
template <int BM>
__device__ __forceinline__ void gemm_core(
    const __hip_bfloat16* __restrict__ a_base, int lda,
    const __hip_bfloat16* __restrict__ b_base, int ldb,
    int m0, int n0, int K,
    __hip_bfloat16* As, __hip_bfloat16* Bs,
    floatx4 (&acc)[BM / 32][4]) {
    constexpr int MF = BM / 32;  // m-frags per wave; also A staging insts
    const int tid  = threadIdx.x;
    const int wave = tid >> 6, lane = tid & 63;
    const int wm = (wave >> 1) * (BM / 2), wn = (wave & 1) * 64;
    const int lrow = lane & 15, kq = lane >> 4;
    const int sw = lrow & 7;

    for (int k0 = 0; k0 < K; k0 += 64) {
        // A-tile: BM rows x 64 bf16 = BM*8 16B units, MF insts/thread
#pragma unroll
        for (int i = 0; i < MF; ++i) {
            const int u = i * 256 + tid;
            const int row = u >> 3, cg = (u & 7) ^ (row & 7);
            const __hip_bfloat16* g =
                a_base + (size_t)(m0 + row) * lda + k0 + cg * 8;
            GLOAD_LDS16(g, As + (size_t)(i * 256 + wave * 64) * 8);
        }
        // B-tile: 128 rows x 64 bf16, 4 insts/thread
#pragma unroll
        for (int i = 0; i < 4; ++i) {
            const int u = i * 256 + tid;
            const int row = u >> 3, cg = (u & 7) ^ (row & 7);
            const __hip_bfloat16* g =
                b_base + (size_t)(n0 + row) * ldb + k0 + cg * 8;
            GLOAD_LDS16(g, Bs + (size_t)(i * 256 + wave * 64) * 8);
        }
        __syncthreads();

#pragma unroll
        for (int s = 0; s < 2; ++s) {  // two 32-K MFMA steps per stage
            short8 af[MF], bfr[4];
#pragma unroll
            for (int t = 0; t < MF; ++t) {
                const int row = wm + t * 16 + lrow;
                const int slot = (s * 4 + kq) ^ sw;
                af[t] = *(const short8*)(As + row * 64 + slot * 8);
            }
#pragma unroll
            for (int t = 0; t < 4; ++t) {
                const int row = wn + t * 16 + lrow;
                const int slot = (s * 4 + kq) ^ sw;
                bfr[t] = *(const short8*)(Bs + row * 64 + slot * 8);
            }
#pragma unroll
            for (int mi = 0; mi < MF; ++mi)
#pragma unroll
                for (int ni = 0; ni < 4; ++ni)
                    acc[mi][ni] = __builtin_amdgcn_mfma_f32_16x16x32_bf16(
                        af[mi], bfr[ni], acc[mi][ni], 0, 0, 0);
        }
        __syncthreads();
    }
}

// ---------------------------------------------------------------------------
// Kernel 0: prep. Blocks [0,3072): x fp32 -> bf16. Blocks [3072,4800):
// w transpose to wt[s][o][d] bf16. Block 4800: zero the row-sum array l.
// ---------------------------------------------------------------------------
__global__ __launch_bounds__(256)
void prep(const float* __restrict__ x, const float* __restrict__ w,
          __hip_bfloat16* __restrict__ xb, __hip_bfloat16* __restrict__ wt,
          float* __restrict__ l) {
    __shared__ float t[32][33];
    const int tid = threadIdx.x;
    if (blockIdx.x < 3072) {
        const size_t i = (size_t)blockIdx.x * 2048 + (size_t)tid * 8;
        float4 a = *(const float4*)(x + i);
        float4 b = *(const float4*)(x + i + 4);
        *(ushort4*)((unsigned short*)xb + i) =
            make_ushort4(f2bfu(a.x), f2bfu(a.y), f2bfu(a.z), f2bfu(a.w));
        *(ushort4*)((unsigned short*)xb + i + 4) =
            make_ushort4(f2bfu(b.x), f2bfu(b.y), f2bfu(b.z), f2bfu(b.w));
    } else if (blockIdx.x < 4800) {
        const int bid = blockIdx.x - 3072;
        const int s = bid / 576, rem = bid % 576;
        const int d0 = (rem / 24) * 32, o0 = (rem % 24) * 32;
        const int tx = tid & 31, ty = tid >> 5;  // 32 x 8
        const float* ws = w + (size_t)s * D_ * OUT_;
        __hip_bfloat16* wts = wt + (size_t)s * OUT_ * D_;
#pragma unroll
        for (int i = 0; i < 4; ++i)
            t[ty + 8 * i][tx] = ws[(size_t)(d0 + ty + 8 * i) * OUT_ + o0 + tx];
        __syncthreads();
#pragma unroll
        for (int i = 0; i < 4; ++i)
            wts[(size_t)(o0 + ty + 8 * i) * D_ + d0 + tx] =
                __float2bfloat16(t[tx][ty + 8 * i]);
    } else {
        float4* l4 = (float4*)l;  // 8192 floats = 2048 float4
#pragma unroll
        for (int i = 0; i < 8; ++i) l4[i * 256 + tid] = make_float4(0, 0, 0, 0);
    }
}

// ---------------------------------------------------------------------------
// Kernel 1: QKV projection (round-3 proven, 52 µs). NT, BM=128, BK=64.
// grid (64, 6, 3). Epilogue via LDS roundtrip -> coalesced short8 stores;
// s=2 writes v TRANSPOSED (vt[b][o][j]).
// ---------------------------------------------------------------------------
__global__ __launch_bounds__(256)
void qkv_mfma(const __hip_bfloat16* __restrict__ xb,
              const __hip_bfloat16* __restrict__ wt,
              __hip_bfloat16* __restrict__ q, __hip_bfloat16* __restrict__ k,
              __hip_bfloat16* __restrict__ vt) {
    __shared__ __align__(16) char smem[34816];  // max(32KB loop, 34KB epi)
    __hip_bfloat16* As = (__hip_bfloat16*)smem;
    __hip_bfloat16* Bs = As + 128 * 64;
    const int s = blockIdx.z;
    const int m0 = blockIdx.x * 128, n0 = blockIdx.y * 128;
    floatx4 acc[4][4] = {};
    gemm_core<128>(xb, D_, wt + (size_t)s * OUT_ * D_, D_, m0, n0, D_, As, Bs,
                   acc);

    const int tid = threadIdx.x, wave = tid >> 6, lane = tid & 63;
    const int wm = (wave >> 1) * 64, wn = (wave & 1) * 64;
    const int lrow = lane & 15, kq = lane >> 4;
    unsigned short* E = (unsigned short*)smem;  // 128 rows x 136 shorts

    if (s < 2) {  // E[m][n]
#pragma unroll
        for (int mi = 0; mi < 4; ++mi)
#pragma unroll
            for (int ni = 0; ni < 4; ++ni) {
                const int n = wn + ni * 16 + lrow;
#pragma unroll
                for (int r = 0; r < 4; ++r)
                    E[(wm + mi * 16 + kq * 4 + r) * 136 + n] =
                        f2bfu(acc[mi][ni][r]);
            }
    } else {  // E[n][m] — transpose for vt
#pragma unroll
        for (int mi = 0; mi < 4; ++mi)
#pragma unroll
            for (int ni = 0; ni < 4; ++ni) {
                const int n = wn + ni * 16 + lrow;
#pragma unroll
                for (int r = 0; r < 4; ++r)
                    E[n * 136 + wm + mi * 16 + kq * 4 + r] =
                        f2bfu(acc[mi][ni][r]);
            }
    }
    __syncthreads();

    if (s < 2) {
        __hip_bfloat16* out = (s == 0) ? q : k;
#pragma unroll
        for (int i = 0; i < 8; ++i) {
            const int u = i * 256 + tid, row = u >> 4, c = u & 15;
            short8 v = *(const short8*)(E + row * 136 + c * 8);
            *(short8*)(out + (size_t)(m0 + row) * OUT_ + n0 + c * 8) = v;
        }
    } else {
        const int b = m0 >> 11, j0 = m0 & 2047;
#pragma unroll
        for (int i = 0; i < 8; ++i) {
            const int u = i * 256 + tid, nrow = u >> 4, c = u & 15;
            short8 v = *(const short8*)(E + nrow * 136 + c * 8);
            *(short8*)(vt + ((size_t)b * OUT_ + n0 + nrow) * N_ + j0 + c * 8) =
                v;
        }
    }
}

// ---------------------------------------------------------------------------
// Kernel 2: scores + exp, NO softmax pass. grid (16, 16, 4).
// P~[b,i,j] = exp(q.k/8 - 8) stored bf16 (dense, ld = N_); row sums
// accumulated into l[b*N_+i] via lrow-butterfly + atomicAdd.
// Max-subtraction-free softmax is safe here: scores sigma~1, max~6 over 4M
// samples; the fixed -8 shift guards to s=96 (exp in fp32). Normalization
// happens in pv's epilogue -> algebraically identical to softmax.
// ---------------------------------------------------------------------------
__global__ __launch_bounds__(256)
void scores_mfma(const __hip_bfloat16* __restrict__ q,
                 const __hip_bfloat16* __restrict__ k,
                 __hip_bfloat16* __restrict__ pt, float* __restrict__ l) {
    __shared__ __align__(16) char smem[34816];
    __hip_bfloat16* As = (__hip_bfloat16*)smem;
    __hip_bfloat16* Bs = As + 128 * 64;
    const int b = blockIdx.z;
    const int m0 = blockIdx.x * 128, n0 = blockIdx.y * 128;
    floatx4 acc[4][4] = {};
    gemm_core<128>(q + (size_t)b * N_ * OUT_, OUT_,
                   k + (size_t)b * N_ * OUT_, OUT_, m0, n0, OUT_, As, Bs, acc);

    const int tid = threadIdx.x, wave = tid >> 6, lane = tid & 63;
    const int wm = (wave >> 1) * 64, wn = (wave & 1) * 64;
    const int lrow = lane & 15, kq = lane >> 4;

    // exp in place + per-lane row partials (sum over this lane's 4 ni cols)
    float rs[4][4];
#pragma unroll
    for (int mi = 0; mi < 4; ++mi)
#pragma unroll
        for (int r = 0; r < 4; ++r) rs[mi][r] = 0.0f;
#pragma unroll
    for (int mi = 0; mi < 4; ++mi)
#pragma unroll
        for (int ni = 0; ni < 4; ++ni)
#pragma unroll
            for (int r = 0; r < 4; ++r) {
                const float e = __expf(acc[mi][ni][r] * 0.125f - 8.0f);
                acc[mi][ni][r] = e;
                rs[mi][r] += e;
            }
    // reduce across the 16 lrow lanes (lane bits 0..3); kq bits untouched
#pragma unroll
    for (int mi = 0; mi < 4; ++mi)
#pragma unroll
        for (int r = 0; r < 4; ++r) {
            float v = rs[mi][r];
            v += __shfl_xor(v, 1, 64);
            v += __shfl_xor(v, 2, 64);
            v += __shfl_xor(v, 4, 64);
            v += __shfl_xor(v, 8, 64);
            if (lrow == 0)
                atomicAdd(&l[(size_t)b * N_ + m0 + wm + mi * 16 + kq * 4 + r],
                          v);
        }

    // LDS roundtrip (E[m][n], stride 136) -> coalesced short8 stores
    unsigned short* E = (unsigned short*)smem;
#pragma unroll
    for (int mi = 0; mi < 4; ++mi)
#pragma unroll
        for (int ni = 0; ni < 4; ++ni) {
            const int n = wn + ni * 16 + lrow;
#pragma unroll
            for (int r = 0; r < 4; ++r)
                E[(wm + mi * 16 + kq * 4 + r) * 136 + n] =
                    f2bfu(acc[mi][ni][r]);
        }
    __syncthreads();
    __hip_bfloat16* pb = pt + (size_t)b * N_ * N_;
#pragma unroll
    for (int i = 0; i < 8; ++i) {
        const int u = i * 256 + tid, row = u >> 4, c = u & 15;
        short8 v = *(const short8*)(E + row * 136 + c * 8);
        *(short8*)(pb + (size_t)(m0 + row) * N_ + n0 + c * 8) = v;
    }
}

// ---------------------------------------------------------------------------
// Kernel 3: out = (P~ . V) / l. NT, BM=64, BK=64. grid (32, 6, 4).
// A = P~ (dense bf16, lda N_), B = vt[b][o][j]. Epilogue divides by l[row].
// ---------------------------------------------------------------------------
__global__ __launch_bounds__(256)
void pv_mfma(const __hip_bfloat16* __restrict__ pt,
             const __hip_bfloat16* __restrict__ vt,
             const float* __restrict__ l, float* __restrict__ out) {
    __shared__ __align__(16) __hip_bfloat16 As[64 * 64];
    __shared__ __align__(16) __hip_bfloat16 Bs[128 * 64];
    const int b = blockIdx.z;
    const int m0 = blockIdx.x * 64, n0 = blockIdx.y * 128;
    floatx4 acc[2][4] = {};
    gemm_core<64>(pt + (size_t)b * N_ * N_, N_,
                  vt + (size_t)b * OUT_ * N_, N_, m0, n0, N_, As, Bs, acc);

    const int tid = threadIdx.x, wave = tid >> 6, lane = tid & 63;
    const int wm = (wave >> 1) * 32, wn = (wave & 1) * 64;
    const int lrow = lane & 15, kq = lane >> 4;
    const float* lb = l + (size_t)b * N_;
    float inv[2][4];
#pragma unroll
    for (int mi = 0; mi < 2; ++mi)
#pragma unroll
        for (int r = 0; r < 4; ++r)
            inv[mi][r] = 1.0f / lb[m0 + wm + mi * 16 + kq * 4 + r];
#pragma unroll
    for (int mi = 0; mi < 2; ++mi)
#pragma unroll
        for (int ni = 0; ni < 4; ++ni) {
            const int n = n0 + wn + ni * 16 + lrow;
#pragma unroll
            for (int r = 0; r < 4; ++r) {
                const int i = m0 + wm + mi * 16 + kq * 4 + r;
                out[((size_t)b * N_ + i) * OUT_ + n] =
                    acc[mi][ni][r] * inv[mi][r];
            }
        }
}

// ---------------------------------------------------------------------------
// ws layout (~87.5 MB; harness provides >= 105 MB, proven in rounds 1-4):
//   [0: q bf16 12.6MB][12.6: k][25.2: vt][37.75: xb 12.6][50.3: wt 3.5MB]
//   [53.9: l fp32 32KB][53.9+: P~ bf16 33.5MB]
// ---------------------------------------------------------------------------
extern "C" void kernel_launch(void* const* d_in, const int* in_sizes, int n_in,
                              void* d_out, int out_size, void* d_ws, size_t ws_size,
                              hipStream_t stream) {
    const float* x = (const float*)d_in[0];
    const float* w = (const float*)d_in[1];
    float* out = (float*)d_out;

    __hip_bfloat16* q  = (__hip_bfloat16*)d_ws;
    __hip_bfloat16* k  = q + (size_t)M_ * OUT_;
    __hip_bfloat16* vt = k + (size_t)M_ * OUT_;
    __hip_bfloat16* xb = vt + (size_t)M_ * OUT_;
    __hip_bfloat16* wt = xb + (size_t)M_ * D_;
    float* l = (float*)(wt + (size_t)3 * OUT_ * D_);
    __hip_bfloat16* pt = (__hip_bfloat16*)(l + M_);

    prep<<<dim3(4801), dim3(256), 0, stream>>>(x, w, xb, wt, l);
    qkv_mfma<<<dim3(M_ / 128, OUT_ / 128, 3), dim3(256), 0, stream>>>(
        xb, wt, q, k, vt);
    scores_mfma<<<dim3(N_ / 128, N_ / 128, B_), dim3(256), 0, stream>>>(
        q, k, pt, l);
    pv_mfma<<<dim3(N_ / 64, OUT_ / 128, B_), dim3(256), 0, stream>>>(
        pt, vt, l, out);
}